// Round 2
// baseline (210.838 us; speedup 1.0000x reference)
//
#include <hip/hip_runtime.h>
#include <hip/hip_bf16.h>
#include <stdint.h>

// TT linear 4096->4096, B=2048, ranks (1,16,16,16,1), modes 8^4.
// R2: W materialized by ONE fused kernel; GEMM re-tiled 64x128 (1024 blocks
// = 4/CU, was 512 = 2/CU latency-bound) with XOR-swizzled LDS staging.

typedef __bf16 bf16_t;
typedef __bf16 bf16x8 __attribute__((ext_vector_type(8)));
typedef float floatx4 __attribute__((ext_vector_type(4)));

#define BATCH_N 2048
#define KD 4096
#define ND 4096

__device__ static inline void load_lds16(const void* g, void* l) {
    __builtin_amdgcn_global_load_lds(
        (const __attribute__((address_space(1))) void*)g,
        (__attribute__((address_space(3))) void*)l, 16, 0, 0);
}

// ---- x fp32 -> bf16, 8 elements/thread --------------------------------
__global__ __launch_bounds__(256) void cvt_x(const float* __restrict__ x,
                                             bf16_t* __restrict__ xb) {
    int t = blockIdx.x * 256 + threadIdx.x;
    const float4* xv = (const float4*)x;
    float4 a = xv[t * 2];
    float4 b = xv[t * 2 + 1];
    bf16x8 o;
    o[0] = (bf16_t)a.x; o[1] = (bf16_t)a.y; o[2] = (bf16_t)a.z; o[3] = (bf16_t)a.w;
    o[4] = (bf16_t)b.x; o[5] = (bf16_t)b.y; o[6] = (bf16_t)b.z; o[7] = (bf16_t)b.w;
    ((bf16x8*)xb)[t] = o;
}

// ---- fused W build: one block per (M23, N01) 64x64 W-tile -------------
// W[j,i], j = M01*64+M23, i = N01*64+N23.
// Per block: stage core slices -> compute P-slice & T1-slice -> contract.
__global__ __launch_bounds__(256) void build_w(const float* __restrict__ c0,
                                               const float* __restrict__ c1,
                                               const float* __restrict__ c2,
                                               const float* __restrict__ c3,
                                               bf16_t* __restrict__ W) {
    __shared__ float c0s[8 * 16];       // [m0][r1]
    __shared__ float c1s[16 * 8 * 16];  // [r1][m1][r2]
    __shared__ float c2s[16 * 8 * 16];  // [r2][n2][r3]
    __shared__ float c3s[16 * 8];       // [r3][n3]
    __shared__ float Ps[64 * 16];       // [m01][r2]
    __shared__ float T1s[16 * 64];      // [r2][n23]
    const int b = blockIdx.x;           // 4096
    const int M23 = b >> 6, N01 = b & 63;
    const int n0 = N01 >> 3, n1 = N01 & 7, m2 = M23 >> 3, m3 = M23 & 7;
    const int t = threadIdx.x;

    if (t < 128) c0s[t] = c0[(t >> 4) * 128 + n0 * 16 + (t & 15)];
    if (t < 128) c3s[t] = c3[((t >> 3) * 8 + m3) * 8 + (t & 7)];
    for (int i = t; i < 2048; i += 256) {
        int r1 = i >> 7, m1 = (i >> 4) & 7, r2 = i & 15;
        c1s[i] = c1[(r1 * 8 + m1) * 128 + n1 * 16 + r2];
    }
    for (int i = t; i < 2048; i += 256) {
        int r2 = i >> 7, n2 = (i >> 4) & 7, r3 = i & 15;
        c2s[i] = c2[(r2 * 8 + m2) * 128 + n2 * 16 + r3];
    }
    __syncthreads();

    for (int i = t; i < 1024; i += 256) {   // Ps[m01][r2]
        int m01 = i >> 4, r2 = i & 15, m0 = m01 >> 3, m1 = m01 & 7;
        float s = 0.f;
#pragma unroll
        for (int r1 = 0; r1 < 16; ++r1)
            s += c0s[m0 * 16 + r1] * c1s[r1 * 128 + m1 * 16 + r2];
        Ps[i] = s;
    }
    for (int i = t; i < 1024; i += 256) {   // T1s[r2][n23]
        int r2 = i >> 6, n23 = i & 63, n2 = n23 >> 3, n3 = n23 & 7;
        float s = 0.f;
#pragma unroll
        for (int r3 = 0; r3 < 16; ++r3)
            s += c2s[r2 * 128 + n2 * 16 + r3] * c3s[r3 * 8 + n3];
        T1s[i] = s;
    }
    __syncthreads();

    const int n23 = t & 63, q = t >> 6;
#pragma unroll
    for (int g = 0; g < 16; ++g) {
        int m01 = q * 16 + g;
        float s = 0.f;
#pragma unroll
        for (int r2 = 0; r2 < 16; ++r2) s += Ps[m01 * 16 + r2] * T1s[r2 * 64 + n23];
        W[(size_t)(m01 * 64 + M23) * 4096 + N01 * 64 + n23] = (bf16_t)s;
    }
}

// ---- BT GEMM: C[m,n] = sum_k A[m,k]*B[n,k] + bias[n] ------------------
// 64x128 tile, BK=32, 256 threads (waves 2x2; each wave 32x64 = 2x4 frags).
// LDS k-chunk XOR-swizzled: phys_chunk = chunk ^ ((row>>1)&3).
__global__ __launch_bounds__(256) void gemm_bt(const bf16_t* __restrict__ A,
                                               const bf16_t* __restrict__ B,
                                               const float* __restrict__ bias,
                                               float* __restrict__ C) {
    __shared__ bf16_t As[64 * 32];    // 4 KB
    __shared__ bf16_t Bs[128 * 32];   // 8 KB
    const int t = threadIdx.x;
    const int bn = blockIdx.x, bm = blockIdx.y;   // 32 x 32
    const int lane = t & 63, wave = t >> 6;
    const int wm = wave >> 1, wn = wave & 1;

    // staging: thread t -> row t>>2, swizzled k-chunk ((t&3)^((t>>3)&3))*8
    const int sr = t >> 2;
    const int sk = ((t & 3) ^ ((t >> 3) & 3)) * 8;
    const bf16_t* Agp = A + (size_t)(bm * 64 + sr) * KD + sk;
    const bf16_t* Bgp = B + (size_t)(bn * 128 + sr) * KD + sk;
    bf16_t* AsW = As + wave * 512;              // wave-uniform LDS bases
    bf16_t* BsW0 = Bs + wave * 512;
    bf16_t* BsW1 = Bs + 2048 + wave * 512;

    floatx4 acc[2][4];
    floatx4 zero = {0.f, 0.f, 0.f, 0.f};
#pragma unroll
    for (int i = 0; i < 2; ++i)
#pragma unroll
        for (int j = 0; j < 4; ++j) acc[i][j] = zero;

    const int fr = lane & 15;                         // fragment row
    const int pk = ((lane >> 4) ^ ((lane >> 1) & 3)) * 8;  // swizzled k-chunk

    for (int k0 = 0; k0 < KD; k0 += 32) {
        __syncthreads();
        load_lds16(Agp + k0, AsW);
        load_lds16(Bgp + k0, BsW0);
        load_lds16(Bgp + (size_t)64 * KD + k0, BsW1);
        __syncthreads();

        bf16x8 af[2], bf[4];
#pragma unroll
        for (int im = 0; im < 2; ++im)
            af[im] = *(const bf16x8*)(As + (wm * 32 + im * 16 + fr) * 32 + pk);
#pragma unroll
        for (int in = 0; in < 4; ++in)
            bf[in] = *(const bf16x8*)(Bs + (wn * 64 + in * 16 + fr) * 32 + pk);
#pragma unroll
        for (int im = 0; im < 2; ++im)
#pragma unroll
            for (int in = 0; in < 4; ++in)
                acc[im][in] = __builtin_amdgcn_mfma_f32_16x16x32_bf16(
                    af[im], bf[in], acc[im][in], 0, 0, 0);
    }

    const int rl = lane >> 4, cl = lane & 15;
    const size_t rbase = (size_t)bm * 64 + wm * 32;
    const int cbase = bn * 128 + wn * 64;
#pragma unroll
    for (int im = 0; im < 2; ++im) {
#pragma unroll
        for (int in = 0; in < 4; ++in) {
            int col = cbase + in * 16 + cl;
            float bv = bias[col];
#pragma unroll
            for (int r = 0; r < 4; ++r) {
                size_t row = rbase + im * 16 + rl * 4 + r;
                C[row * ND + col] = acc[im][in][r] + bv;
            }
        }
    }
}

extern "C" void kernel_launch(void* const* d_in, const int* in_sizes, int n_in,
                              void* d_out, int out_size, void* d_ws, size_t ws_size,
                              hipStream_t stream) {
    const float* x  = (const float*)d_in[0];
    const float* c0 = (const float*)d_in[1];
    const float* c1 = (const float*)d_in[2];
    const float* c2 = (const float*)d_in[3];
    const float* c3 = (const float*)d_in[4];
    const float* bias = (const float*)d_in[5];
    float* out = (float*)d_out;

    char* ws = (char*)d_ws;
    bf16_t* Xb = (bf16_t*)ws;                 // 16 MiB
    bf16_t* W  = (bf16_t*)(ws + (16u << 20)); // 32 MiB

    cvt_x<<<4096, 256, 0, stream>>>(x, Xb);
    build_w<<<4096, 256, 0, stream>>>(c0, c1, c2, c3, W);
    dim3 grid(ND / 128, BATCH_N / 64);
    gemm_bt<<<grid, 256, 0, stream>>>(Xb, W, bias, out);
}

// Round 3
// 183.239 us; speedup vs baseline: 1.1506x; 1.1506x over previous
//
#include <hip/hip_runtime.h>
#include <hip/hip_bf16.h>
#include <stdint.h>

// TT linear 4096->4096, B=2048, ranks (1,16,16,16,1), modes 8^4.
// R3: W materialized (fused kernel), GEMM 128x128 tile with BK=64
// (32 MFMA/wave per barrier pair, was 16) + XOR-swizzled LDS (0 conflicts).

typedef __bf16 bf16_t;
typedef __bf16 bf16x8 __attribute__((ext_vector_type(8)));
typedef float floatx4 __attribute__((ext_vector_type(4)));

#define BATCH_N 2048
#define KD 4096
#define ND 4096

__device__ static inline void load_lds16(const void* g, void* l) {
    __builtin_amdgcn_global_load_lds(
        (const __attribute__((address_space(1))) void*)g,
        (__attribute__((address_space(3))) void*)l, 16, 0, 0);
}

// ---- x fp32 -> bf16, 8 elements/thread --------------------------------
__global__ __launch_bounds__(256) void cvt_x(const float* __restrict__ x,
                                             bf16_t* __restrict__ xb) {
    int t = blockIdx.x * 256 + threadIdx.x;
    const float4* xv = (const float4*)x;
    float4 a = xv[t * 2];
    float4 b = xv[t * 2 + 1];
    bf16x8 o;
    o[0] = (bf16_t)a.x; o[1] = (bf16_t)a.y; o[2] = (bf16_t)a.z; o[3] = (bf16_t)a.w;
    o[4] = (bf16_t)b.x; o[5] = (bf16_t)b.y; o[6] = (bf16_t)b.z; o[7] = (bf16_t)b.w;
    ((bf16x8*)xb)[t] = o;
}

// ---- fused W build: one block per (M23, N01) 64x64 W-tile -------------
__global__ __launch_bounds__(256) void build_w(const float* __restrict__ c0,
                                               const float* __restrict__ c1,
                                               const float* __restrict__ c2,
                                               const float* __restrict__ c3,
                                               bf16_t* __restrict__ W) {
    __shared__ float c0s[8 * 16];       // [m0][r1]
    __shared__ float c1s[16 * 8 * 16];  // [r1][m1][r2]
    __shared__ float c2s[16 * 8 * 16];  // [r2][n2][r3]
    __shared__ float c3s[16 * 8];       // [r3][n3]
    __shared__ float Ps[64 * 16];       // [m01][r2]
    __shared__ float T1s[16 * 64];      // [r2][n23]
    const int b = blockIdx.x;           // 4096
    const int M23 = b >> 6, N01 = b & 63;
    const int n0 = N01 >> 3, n1 = N01 & 7, m2 = M23 >> 3, m3 = M23 & 7;
    const int t = threadIdx.x;

    if (t < 128) c0s[t] = c0[(t >> 4) * 128 + n0 * 16 + (t & 15)];
    if (t < 128) c3s[t] = c3[((t >> 3) * 8 + m3) * 8 + (t & 7)];
    for (int i = t; i < 2048; i += 256) {
        int r1 = i >> 7, m1 = (i >> 4) & 7, r2 = i & 15;
        c1s[i] = c1[(r1 * 8 + m1) * 128 + n1 * 16 + r2];
    }
    for (int i = t; i < 2048; i += 256) {
        int r2 = i >> 7, n2 = (i >> 4) & 7, r3 = i & 15;
        c2s[i] = c2[(r2 * 8 + m2) * 128 + n2 * 16 + r3];
    }
    __syncthreads();

    for (int i = t; i < 1024; i += 256) {   // Ps[m01][r2]
        int m01 = i >> 4, r2 = i & 15, m0 = m01 >> 3, m1 = m01 & 7;
        float s = 0.f;
#pragma unroll
        for (int r1 = 0; r1 < 16; ++r1)
            s += c0s[m0 * 16 + r1] * c1s[r1 * 128 + m1 * 16 + r2];
        Ps[i] = s;
    }
    for (int i = t; i < 1024; i += 256) {   // T1s[r2][n23]
        int r2 = i >> 6, n23 = i & 63, n2 = n23 >> 3, n3 = n23 & 7;
        float s = 0.f;
#pragma unroll
        for (int r3 = 0; r3 < 16; ++r3)
            s += c2s[r2 * 128 + n2 * 16 + r3] * c3s[r3 * 8 + n3];
        T1s[i] = s;
    }
    __syncthreads();

    const int n23 = t & 63, q = t >> 6;
#pragma unroll
    for (int g = 0; g < 16; ++g) {
        int m01 = q * 16 + g;
        float s = 0.f;
#pragma unroll
        for (int r2 = 0; r2 < 16; ++r2) s += Ps[m01 * 16 + r2] * T1s[r2 * 64 + n23];
        W[(size_t)(m01 * 64 + M23) * 4096 + N01 * 64 + n23] = (bf16_t)s;
    }
}

// ---- BT GEMM: C[m,n] = sum_k A[m,k]*B[n,k] + bias[n] ------------------
// 128x128 tile, BK=64, 256 threads (waves 2x2, each 64x64 = 4x4 frags,
// 32 MFMA per K-iter). LDS row-major [row][64k], 16B-chunk XOR swizzle:
// phys_chunk = logical_chunk ^ (row & 7). Staging via global_load_lds w=16;
// swizzle applied on the global-source side (LDS dest must be lane-linear).
__global__ __launch_bounds__(256, 2) void gemm_bt(const bf16_t* __restrict__ A,
                                                  const bf16_t* __restrict__ B,
                                                  const float* __restrict__ bias,
                                                  float* __restrict__ C) {
    __shared__ bf16_t As[128 * 64];   // 16 KB
    __shared__ bf16_t Bs[128 * 64];   // 16 KB
    const int t = threadIdx.x;
    const int bn = blockIdx.x, bm = blockIdx.y;   // 32 x 16
    const int lane = t & 63, wave = t >> 6;
    const int wm = wave >> 1, wn = wave & 1;

    // staging: call j (0..3), wave w: rows [(j*4+w)*8, +8) of the 128-row tile.
    // lane l: row offset l>>3, logical 16B-chunk (l&7)^(l>>3)  [phys = l&7]
    const int srow = lane >> 3;                 // 0..7
    const int lc = (lane & 7) ^ srow;           // swizzled logical chunk
    const bf16_t* Agp = A + (size_t)(bm * 128 + wave * 8 + srow) * KD + lc * 8;
    const bf16_t* Bgp = B + (size_t)(bn * 128 + wave * 8 + srow) * KD + lc * 8;
    bf16_t* AsW = As + wave * 512;              // wave-uniform LDS bases
    bf16_t* BsW = Bs + wave * 512;

    floatx4 acc[4][4];
    floatx4 zero = {0.f, 0.f, 0.f, 0.f};
#pragma unroll
    for (int i = 0; i < 4; ++i)
#pragma unroll
        for (int j = 0; j < 4; ++j) acc[i][j] = zero;

    const int fr = lane & 15;                   // fragment row/col
    const int fc = lane >> 4;                   // base chunk (0..3)

    for (int k0 = 0; k0 < KD; k0 += 64) {
        __syncthreads();
#pragma unroll
        for (int j = 0; j < 4; ++j) {
            load_lds16(Agp + (size_t)(j * 32) * KD + k0, AsW + j * 2048);
            load_lds16(Bgp + (size_t)(j * 32) * KD + k0, BsW + j * 2048);
        }
        __syncthreads();

#pragma unroll
        for (int kk = 0; kk < 2; ++kk) {
            const int pA = (fc + kk * 4) ^ (fr & 7);   // phys chunk
            bf16x8 af[4], bf[4];
#pragma unroll
            for (int im = 0; im < 4; ++im)
                af[im] = *(const bf16x8*)(As + (wm * 64 + im * 16 + fr) * 64 + pA * 8);
#pragma unroll
            for (int in = 0; in < 4; ++in)
                bf[in] = *(const bf16x8*)(Bs + (wn * 64 + in * 16 + fr) * 64 + pA * 8);
#pragma unroll
            for (int im = 0; im < 4; ++im)
#pragma unroll
                for (int in = 0; in < 4; ++in)
                    acc[im][in] = __builtin_amdgcn_mfma_f32_16x16x32_bf16(
                        af[im], bf[in], acc[im][in], 0, 0, 0);
        }
    }

    // epilogue: D[m=(lane>>4)*4+reg][n=lane&15]
    const int rl = lane >> 4, cl = lane & 15;
    const size_t rbase = (size_t)bm * 128 + wm * 64;
    const int cbase = bn * 128 + wn * 64;
#pragma unroll
    for (int im = 0; im < 4; ++im) {
#pragma unroll
        for (int in = 0; in < 4; ++in) {
            int col = cbase + in * 16 + cl;
            float bv = bias[col];
#pragma unroll
            for (int r = 0; r < 4; ++r) {
                size_t row = rbase + im * 16 + rl * 4 + r;
                C[row * ND + col] = acc[im][in][r] + bv;
            }
        }
    }
}

extern "C" void kernel_launch(void* const* d_in, const int* in_sizes, int n_in,
                              void* d_out, int out_size, void* d_ws, size_t ws_size,
                              hipStream_t stream) {
    const float* x  = (const float*)d_in[0];
    const float* c0 = (const float*)d_in[1];
    const float* c1 = (const float*)d_in[2];
    const float* c2 = (const float*)d_in[3];
    const float* c3 = (const float*)d_in[4];
    const float* bias = (const float*)d_in[5];
    float* out = (float*)d_out;

    char* ws = (char*)d_ws;
    bf16_t* Xb = (bf16_t*)ws;                 // 16 MiB
    bf16_t* W  = (bf16_t*)(ws + (16u << 20)); // 32 MiB

    cvt_x<<<4096, 256, 0, stream>>>(x, Xb);
    build_w<<<4096, 256, 0, stream>>>(c0, c1, c2, c3, W);
    dim3 grid(ND / 128, BATCH_N / 128);
    gemm_bt<<<grid, 256, 0, stream>>>(Xb, W, bias, out);
}